// Round 4
// baseline (589.183 us; speedup 1.0000x reference)
//
#include <hip/hip_runtime.h>

typedef unsigned short u16;
typedef __bf16 bf16x8 __attribute__((ext_vector_type(8)));
typedef float f32x4 __attribute__((ext_vector_type(4)));
typedef u16 u16x8 __attribute__((ext_vector_type(8)));

static constexpr int S_LEN  = 2048;
static constexpr int DMODEL = 2048;
static constexpr int NKV    = 4;
static constexpr int HD     = 128;

__device__ __forceinline__ float bf2f(u16 h) {
  unsigned u = ((unsigned)h) << 16;
  return __builtin_bit_cast(float, u);
}
__device__ __forceinline__ u16 f2bf(float f) {
  unsigned u = __builtin_bit_cast(unsigned, f);
  u += 0x7fffu + ((u >> 16) & 1u);
  return (u16)(u >> 16);
}
__device__ __forceinline__ bf16x8 as_bf(u16x8 v) { return __builtin_bit_cast(bf16x8, v); }

// 8 fp32 -> 8 bf16 (RNE), two 16B loads
__device__ __forceinline__ u16x8 cvt8(const float* p) {
  f32x4 lo = *(const f32x4*)p;
  f32x4 hi = *(const f32x4*)(p + 4);
  u16x8 r;
#pragma unroll
  for (int j = 0; j < 4; ++j) { r[j] = f2bf(lo[j]); r[j + 4] = f2bf(hi[j]); }
  return r;
}

// ---------------------------------------------------------------------------
// GEMM: C[M,N] = A[M,K] @ B[N,K]^T, bf16 MFMA fp32-accum.
// AF/BF: operands are fp32 (convert during staging) vs bf16.
// CF: C written as fp32 (1) or bf16 (0).
// 128x128 tile, BK=32, 4 waves each 64x64 of 16x16x32 MFMA.
// Blocks >= split use (Bw2, C2) — fuses the K and V projections in one launch.
// ---------------------------------------------------------------------------
template <int AF, int BF, int CF>
__global__ __launch_bounds__(256) void gemm_bt(
    const void* __restrict__ Ap, const void* __restrict__ Bwp, void* __restrict__ Cp,
    const void* __restrict__ Bw2p, void* __restrict__ C2p,
    int M, int N, int K, int split)
{
  __shared__ u16 As[128 * 32];
  __shared__ u16 Bs[128 * 32];
  int bx = blockIdx.x;
  const void* Bp = Bwp;
  void* Cq = Cp;
  if (bx >= split) { Bp = Bw2p; Cq = C2p; bx -= split; }
  const int nbn = N >> 7;
  const int bm = bx / nbn, bn = bx % nbn;
  const int tid = threadIdx.x, wave = tid >> 6, lane = tid & 63;
  const int wm = (wave & 1) << 6, wn = (wave >> 1) << 6;
  const long m0 = (long)bm << 7, n0 = (long)bn << 7;

  f32x4 acc[4][4] = {};

  // staging: wave stages rows [wave*32, wave*32+32); lane l covers row l/4,
  // chunk (l%4)*8 elems; two row-groups 16 apart per instruction pair.
  const int srow = (wave << 5) + (lane >> 2);
  const int sch  = (lane & 3) << 3;
  const long aoff = (m0 + srow) * (long)K + sch;
  const long boff = (n0 + srow) * (long)K + sch;
  const long rstep = (long)16 * K;
  u16* la = As + (wave << 10) + (lane << 3);
  u16* lb = Bs + (wave << 10) + (lane << 3);

  const int fr = lane & 15, fc = (lane >> 4) << 3;

  for (int k0 = 0; k0 < K; k0 += 32) {
    u16x8 a0, a1, b0, b1;
    if (AF) {
      a0 = cvt8((const float*)Ap + aoff + k0);
      a1 = cvt8((const float*)Ap + aoff + k0 + rstep);
    } else {
      a0 = *(const u16x8*)((const u16*)Ap + aoff + k0);
      a1 = *(const u16x8*)((const u16*)Ap + aoff + k0 + rstep);
    }
    if (BF) {
      b0 = cvt8((const float*)Bp + boff + k0);
      b1 = cvt8((const float*)Bp + boff + k0 + rstep);
    } else {
      b0 = *(const u16x8*)((const u16*)Bp + boff + k0);
      b1 = *(const u16x8*)((const u16*)Bp + boff + k0 + rstep);
    }
    __syncthreads();                     // prev iteration's LDS reads done
    *(u16x8*)la         = a0;
    *(u16x8*)(la + 512) = a1;            // +16 rows
    *(u16x8*)lb         = b0;
    *(u16x8*)(lb + 512) = b1;
    __syncthreads();
    bf16x8 af[4], bf[4];
#pragma unroll
    for (int i = 0; i < 4; ++i)
      af[i] = as_bf(*(const u16x8*)&As[(wm + (i << 4) + fr) * 32 + fc]);
#pragma unroll
    for (int i = 0; i < 4; ++i)
      bf[i] = as_bf(*(const u16x8*)&Bs[(wn + (i << 4) + fr) * 32 + fc]);
#pragma unroll
    for (int mi = 0; mi < 4; ++mi)
#pragma unroll
      for (int ni = 0; ni < 4; ++ni)
        acc[mi][ni] = __builtin_amdgcn_mfma_f32_16x16x32_bf16(af[mi], bf[ni], acc[mi][ni], 0, 0, 0);
  }

  // epilogue: C/D layout col=lane&15, row=(lane>>4)*4+reg (m89-verified)
  const int er = (lane >> 4) << 2, ec = lane & 15;
#pragma unroll
  for (int mi = 0; mi < 4; ++mi)
#pragma unroll
    for (int ni = 0; ni < 4; ++ni) {
      const long base = (m0 + wm + (mi << 4) + er) * N + (n0 + wn + (ni << 4) + ec);
      if (CF) {
        float* cp = (float*)Cq + base;
#pragma unroll
        for (int r = 0; r < 4; ++r) cp[(long)r * N] = acc[mi][ni][r];
      } else {
        u16* cp = (u16*)Cq + base;
#pragma unroll
        for (int r = 0; r < 4; ++r) cp[(long)r * N] = f2bf(acc[mi][ni][r]);
      }
    }
}

// ---------------------------------------------------------------------------
// RMSNorm + RoPE over head rows of 128 (bf16 buf, fp32 params). One wave per
// row; lane holds elems (i, i+64) = the rotate-half pair. scale folds 1/sqrt(HD).
// ---------------------------------------------------------------------------
__global__ __launch_bounds__(256) void norm_rope(
    u16* __restrict__ buf, const float* __restrict__ w,
    const float* __restrict__ cosb, const float* __restrict__ sinb,
    int sshift, float scale)
{
  const int row  = blockIdx.x * 4 + (threadIdx.x >> 6);
  const int lane = threadIdx.x & 63;
  const int s = (row >> sshift) & (S_LEN - 1);
  u16* p = buf + (long)row * HD;
  float t1 = bf2f(p[lane]), t2 = bf2f(p[lane + 64]);
  float ss = t1 * t1 + t2 * t2;
#pragma unroll
  for (int off = 32; off; off >>= 1) ss += __shfl_xor(ss, off);
  const float r = rsqrtf(ss * (1.0f / 128.0f) + 1e-5f);
  t1 *= r * w[lane];
  t2 *= r * w[lane + 64];
  const float* cp = cosb + s * HD;
  const float* sp = sinb + s * HD;
  const float o1 = (t1 * cp[lane]      - t2 * sp[lane])      * scale;
  const float o2 = (t2 * cp[lane + 64] + t1 * sp[lane + 64]) * scale;
  p[lane]      = f2bf(o1);
  p[lane + 64] = f2bf(o2);
}

// ---------------------------------------------------------------------------
// V (B*S, KV*HD) -> Vt (B*KV, HD, S)
// ---------------------------------------------------------------------------
__global__ __launch_bounds__(256) void transpose_v(const u16* __restrict__ v,
                                                   u16* __restrict__ vt)
{
  const int idx = blockIdx.x * 256 + threadIdx.x;   // 262144 total
  const int t   = idx & (S_LEN - 1);
  const int hd0 = ((idx >> 11) & 15) << 3;
  const int bkv = idx >> 15;                        // 0..7 = b*4+kv
  const u16* vp = v + ((long)(bkv >> 2) * S_LEN + t) * 512 + ((bkv & 3) << 7) + hd0;
  u16x8 d = *(const u16x8*)vp;
  u16* op = vt + ((long)bkv * HD + hd0) * S_LEN + t;
#pragma unroll
  for (int j = 0; j < 8; ++j) op[(long)j * S_LEN] = d[j];
}

// ---------------------------------------------------------------------------
// Flash attention (causal, GQA). Block = (b, h, 128-row q-tile), 4 waves each
// own 32 q rows. K/Vt tiles 128x128 in LDS with XOR chunk swizzle. P reuses
// the K buffer (wave-private rows) to convert MFMA C-layout -> A-layout.
// ---------------------------------------------------------------------------
__global__ __launch_bounds__(256, 2) void flash(
    const u16* __restrict__ q, const u16* __restrict__ k,
    const u16* __restrict__ vt, u16* __restrict__ ctx)
{
  __shared__ u16 Ks[128 * 128];   // K tile; reused for P after QK^T
  __shared__ u16 Vs[128 * 128];   // Vt tile (rows = hd, cols = t)
  const int tid = threadIdx.x, wave = tid >> 6, lane = tid & 63;
  const int bx  = blockIdx.x;
  const int qtr = bx & 15;
  const int bh  = bx >> 4;                          // 0..31 = b*16+h
  const int qt  = (bx < 256) ? (15 - qtr) : qtr;    // balance causal wedge
  const int b   = bh >> 4, h = bh & 15;
  const int kv  = h >> 2;                           // G = 4
  const int q0  = qt << 7;

  const int fr = lane & 15, fhi = lane >> 4;
  const int fc = fhi << 3;

  // Q fragments (A-layout: m=lane&15, k=fhi*8+j), RoPE'd + scaled already
  bf16x8 qf[2][4];
#pragma unroll
  for (int mi = 0; mi < 2; ++mi) {
    const long s = q0 + (wave << 5) + (mi << 4) + fr;
    const u16* qp = q + ((long)b * S_LEN + s) * DMODEL + h * HD;
#pragma unroll
    for (int kb = 0; kb < 4; ++kb)
      qf[mi][kb] = as_bf(*(const u16x8*)(qp + (kb << 5) + fc));
  }

  f32x4 O[2][8] = {};
  float mS[2][4], lS[2][4];
#pragma unroll
  for (int mi = 0; mi < 2; ++mi)
#pragma unroll
    for (int r = 0; r < 4; ++r) { mS[mi][r] = -1e30f; lS[mi][r] = 0.f; }

  const u16* kbase = k + ((long)b * S_LEN) * 512 + kv * HD;
  const u16* vbase = vt + ((long)(b * NKV + kv)) * HD * S_LEN;

  for (int jt = 0; jt <= qt; ++jt) {
    const int t0 = jt << 7;
    __syncthreads();   // previous iter's LDS reads done
    // stage K then Vt tile. LDS[row][cc] holds global chunk cc ^ (row&15).
    {
      u16x8 tmp[8];
#pragma unroll
      for (int i = 0; i < 8; ++i) {
        const int row = (wave << 5) + (i << 2) + fhi;
        const int gc  = fr ^ (row & 15);
        tmp[i] = *(const u16x8*)(kbase + (long)(t0 + row) * 512 + (gc << 3));
      }
#pragma unroll
      for (int i = 0; i < 8; ++i)
        *(u16x8*)(Ks + ((wave << 5) + (i << 2)) * 128 + (lane << 3)) = tmp[i];
#pragma unroll
      for (int i = 0; i < 8; ++i) {
        const int row = (wave << 5) + (i << 2) + fhi;
        const int gc  = fr ^ (row & 15);
        tmp[i] = *(const u16x8*)(vbase + (long)row * S_LEN + t0 + (gc << 3));
      }
#pragma unroll
      for (int i = 0; i < 8; ++i)
        *(u16x8*)(Vs + ((wave << 5) + (i << 2)) * 128 + (lane << 3)) = tmp[i];
    }
    __syncthreads();

    // S = Q K^T  (B operand: n = t = ni*16+fr, k = kb*32 + fhi*8 + j)
    f32x4 Sac[2][8] = {};
#pragma unroll
    for (int ni = 0; ni < 8; ++ni) {
      const int t = (ni << 4) + fr;
      bf16x8 kf[4];
#pragma unroll
      for (int kb = 0; kb < 4; ++kb) {
        const int cc = ((kb << 2) + fhi) ^ (t & 15);
        kf[kb] = as_bf(*(const u16x8*)&Ks[t * 128 + (cc << 3)]);
      }
#pragma unroll
      for (int mi = 0; mi < 2; ++mi)
#pragma unroll
        for (int kb = 0; kb < 4; ++kb)
          Sac[mi][ni] = __builtin_amdgcn_mfma_f32_16x16x32_bf16(qf[mi][kb], kf[kb], Sac[mi][ni], 0, 0, 0);
    }

    // causal mask only on the diagonal tile
    if (jt == qt) {
      const int rowb = fhi << 2;
#pragma unroll
      for (int mi = 0; mi < 2; ++mi)
#pragma unroll
        for (int ni = 0; ni < 8; ++ni) {
          const int tc = (ni << 4) + fr;
          const int sr = (wave << 5) + (mi << 4) + rowb;
#pragma unroll
          for (int r = 0; r < 4; ++r)
            if (tc > sr + r) Sac[mi][ni][r] = -1e30f;
        }
    }

    // online softmax; row state per (mi, reg), reduced over 16-lane groups
    float alpha[2][4];
#pragma unroll
    for (int mi = 0; mi < 2; ++mi) {
      float rmax[4] = {-1e30f, -1e30f, -1e30f, -1e30f};
#pragma unroll
      for (int ni = 0; ni < 8; ++ni)
#pragma unroll
        for (int r = 0; r < 4; ++r) rmax[r] = fmaxf(rmax[r], Sac[mi][ni][r]);
#pragma unroll
      for (int r = 0; r < 4; ++r) {
#pragma unroll
        for (int off = 1; off < 16; off <<= 1)
          rmax[r] = fmaxf(rmax[r], __shfl_xor(rmax[r], off));
        const float mn = fmaxf(mS[mi][r], rmax[r]);
        alpha[mi][r] = __expf(mS[mi][r] - mn);
        mS[mi][r] = mn;
      }
      float rsum[4] = {0.f, 0.f, 0.f, 0.f};
#pragma unroll
      for (int ni = 0; ni < 8; ++ni)
#pragma unroll
        for (int r = 0; r < 4; ++r) {
          const float e = __expf(Sac[mi][ni][r] - mS[mi][r]);
          Sac[mi][ni][r] = e;
          rsum[r] += e;
        }
#pragma unroll
      for (int r = 0; r < 4; ++r) {
#pragma unroll
        for (int off = 1; off < 16; off <<= 1)
          rsum[r] += __shfl_xor(rsum[r], off);
        lS[mi][r] = lS[mi][r] * alpha[mi][r] + rsum[r];
      }
#pragma unroll
      for (int nj = 0; nj < 8; ++nj)
#pragma unroll
        for (int r = 0; r < 4; ++r) O[mi][nj][r] *= alpha[mi][r];
    }

    __syncthreads();   // all waves done reading K fragments from Ks

    // write P (bf16) into Ks at this wave's own q rows, same swizzle as reads
    {
      const int rowb = fhi << 2;
#pragma unroll
      for (int mi = 0; mi < 2; ++mi)
#pragma unroll
        for (int ni = 0; ni < 8; ++ni) {
          const int c  = (ni << 1) + (fr >> 3);
          const int ce = fr & 7;
#pragma unroll
          for (int r = 0; r < 4; ++r) {
            const int row = (wave << 5) + (mi << 4) + rowb + r;
            const int cc  = c ^ (row & 15);
            Ks[row * 128 + (cc << 3) + ce] = f2bf(Sac[mi][ni][r]);
          }
        }
    }
    asm volatile("" ::: "memory");   // keep P reads after P writes

    // O += P @ V  (P rows are wave-private: no barrier needed)
    {
      bf16x8 pf[2][4];
#pragma unroll
      for (int mi = 0; mi < 2; ++mi) {
        const int row = (wave << 5) + (mi << 4) + fr;
#pragma unroll
        for (int kt = 0; kt < 4; ++kt) {
          const int cc = ((kt << 2) + fhi) ^ (row & 15);
          pf[mi][kt] = as_bf(*(const u16x8*)&Ks[row * 128 + (cc << 3)]);
        }
      }
#pragma unroll
      for (int nj = 0; nj < 8; ++nj) {
        const int hd = (nj << 4) + fr;
        bf16x8 vf[4];
#pragma unroll
        for (int kt = 0; kt < 4; ++kt) {
          const int cc = ((kt << 2) + fhi) ^ (hd & 15);
          vf[kt] = as_bf(*(const u16x8*)&Vs[hd * 128 + (cc << 3)]);
        }
#pragma unroll
        for (int mi = 0; mi < 2; ++mi)
#pragma unroll
          for (int kt = 0; kt < 4; ++kt)
            O[mi][nj] = __builtin_amdgcn_mfma_f32_16x16x32_bf16(pf[mi][kt], vf[kt], O[mi][nj], 0, 0, 0);
      }
    }
  }

  // epilogue: O /= l, write ctx rows (b, s, h*HD + hd)
  {
    const int rowb = fhi << 2;
#pragma unroll
    for (int mi = 0; mi < 2; ++mi) {
      float inv[4];
#pragma unroll
      for (int r = 0; r < 4; ++r) inv[r] = 1.0f / lS[mi][r];
#pragma unroll
      for (int r = 0; r < 4; ++r) {
        const long s = q0 + (wave << 5) + (mi << 4) + rowb + r;
        u16* cp = ctx + ((long)b * S_LEN + s) * DMODEL + h * HD;
#pragma unroll
        for (int nj = 0; nj < 8; ++nj)
          cp[(nj << 4) + fr] = f2bf(O[mi][nj][r] * inv[r]);
      }
    }
  }
}

// ---------------------------------------------------------------------------
extern "C" void kernel_launch(void* const* d_in, const int* in_sizes, int n_in,
                              void* d_out, int out_size, void* d_ws, size_t ws_size,
                              hipStream_t stream) {
  const float* x    = (const float*)d_in[0];
  // d_in[1] = mask (causal, analytic — unused)
  const float* cosb = (const float*)d_in[2];
  const float* sinb = (const float*)d_in[3];
  const float* Wq   = (const float*)d_in[4];
  const float* Wk   = (const float*)d_in[5];
  const float* Wv   = (const float*)d_in[6];
  const float* Wo   = (const float*)d_in[7];
  const float* qw   = (const float*)d_in[8];
  const float* kw   = (const float*)d_in[9];

  // qb (bf16, 16.7 MB) lives in d_out (fp32, 33.5 MB) — dead before final GEMM
  u16* qb  = (u16*)d_out;            // (B*S, 2048) bf16
  u16* kb  = (u16*)d_ws;             // (B*S, 512)       2097152 elems
  u16* vb  = kb  + 2097152;          // (B*S, 512)       2097152
  u16* vtb = vb  + 2097152;          // (B*KV, HD, S)    2097152
  u16* ctx = vtb + 2097152;          // (B*S, 2048)      8388608
  float* out = (float*)d_out;

  gemm_bt<1, 1, 0><<<dim3(512), dim3(256), 0, stream>>>(
      x, Wq, qb, (const void*)nullptr, (void*)nullptr, 4096, 2048, 2048, 1 << 30);
  gemm_bt<1, 1, 0><<<dim3(256), dim3(256), 0, stream>>>(
      x, Wk, kb, Wv, vb, 4096, 512, 2048, 128);
  norm_rope<<<dim3(16384), dim3(256), 0, stream>>>(
      qb, qw, cosb, sinb, 4, 0.08838834764831845f);
  norm_rope<<<dim3(4096), dim3(256), 0, stream>>>(
      kb, kw, cosb, sinb, 2, 1.0f);
  transpose_v<<<dim3(1024), dim3(256), 0, stream>>>(vb, vtb);
  flash<<<dim3(512), dim3(256), 0, stream>>>(qb, kb, vtb, ctx);
  gemm_bt<0, 1, 1><<<dim3(512), dim3(256), 0, stream>>>(
      ctx, Wo, out, (const void*)nullptr, (void*)nullptr, 4096, 2048, 2048, 1 << 30);
}

// Round 5
// 348.173 us; speedup vs baseline: 1.6922x; 1.6922x over previous
//
#include <hip/hip_runtime.h>

typedef unsigned short u16;
typedef __bf16 bf16x8 __attribute__((ext_vector_type(8)));
typedef float f32x4 __attribute__((ext_vector_type(4)));
typedef u16 u16x8 __attribute__((ext_vector_type(8)));
typedef u16 u16x4 __attribute__((ext_vector_type(4)));

static constexpr int S_LEN  = 2048;
static constexpr int DMODEL = 2048;
static constexpr int NKV    = 4;
static constexpr int HD     = 128;

__device__ __forceinline__ u16 f2bf(float f) {
  unsigned u = __builtin_bit_cast(unsigned, f);
  u += 0x7fffu + ((u >> 16) & 1u);
  return (u16)(u >> 16);
}
__device__ __forceinline__ float bf2f(u16 h) {
  unsigned u = ((unsigned)h) << 16;
  return __builtin_bit_cast(float, u);
}
__device__ __forceinline__ bf16x8 as_bf(u16x8 v) { return __builtin_bit_cast(bf16x8, v); }

__device__ __forceinline__ u16x8 cvt8(const float* p) {
  f32x4 lo = *(const f32x4*)p;
  f32x4 hi = *(const f32x4*)(p + 4);
  u16x8 r;
#pragma unroll
  for (int j = 0; j < 4; ++j) { r[j] = f2bf(lo[j]); r[j + 4] = f2bf(hi[j]); }
  return r;
}

// async global->LDS DMA, 16B/lane; LDS dest = wave-uniform base + lane*16.
__device__ __forceinline__ void gld16(const u16* g, u16* l) {
  auto gp = (const __attribute__((address_space(1))) unsigned*)(unsigned long long)g;
  auto lp = (__attribute__((address_space(3))) unsigned*)(unsigned)(unsigned long long)l;
  __builtin_amdgcn_global_load_lds(gp, lp, 16, 0, 0);
}

// ---------------------------------------------------------------------------
// fp32 -> bf16 conversion kernels
// ---------------------------------------------------------------------------
__global__ __launch_bounds__(256) void cvt1(const float* __restrict__ in,
                                            u16* __restrict__ out, int n8) {
  const int i = blockIdx.x * 256 + threadIdx.x;
  if (i < n8) *(u16x8*)(out + (long)i * 8) = cvt8(in + (long)i * 8);
}
// Wq (2048x2048) ; Wk (512x2048) ; Wv (512x2048) -> contiguous Wall (3072x2048)
__global__ __launch_bounds__(256) void cvt3(const float* __restrict__ a,
                                            const float* __restrict__ b,
                                            const float* __restrict__ c,
                                            u16* __restrict__ out) {
  const int i = blockIdx.x * 256 + threadIdx.x;     // 786432 total
  const float* src; long j;
  if (i < 524288)      { src = a; j = i; }
  else if (i < 655360) { src = b; j = i - 524288; }
  else                 { src = c; j = i - 655360; }
  *(u16x8*)(out + (long)i * 8) = cvt8(src + j * 8);
}

// ---------------------------------------------------------------------------
// Fused QKV projection: C[4096,3072] = xb[4096,2048] @ Wall[3072,2048]^T.
// m97 recipe: 128x128 tile, BK=32, global_load_lds width-16 staging.
// Output split per bn: q (N=2048) / k (N=512) / v (N=512).
// ---------------------------------------------------------------------------
__global__ __launch_bounds__(256) void gemm_qkv(
    const u16* __restrict__ A, const u16* __restrict__ Bw,
    u16* __restrict__ Cq, u16* __restrict__ Ck, u16* __restrict__ Cv)
{
  constexpr int K = 2048;
  __shared__ u16 As[128 * 32];
  __shared__ u16 Bs[128 * 32];
  const int bx = blockIdx.x;
  const int bm = bx / 24, bn = bx % 24;
  const int tid = threadIdx.x, wave = tid >> 6, lane = tid & 63;
  const int wm = (wave & 1) << 6, wn = (wave >> 1) << 6;
  const long m0 = (long)bm << 7, n0 = (long)bn << 7;

  f32x4 acc[4][4] = {};

  const int srow = (wave << 5) + (lane >> 2);
  const int sch  = (lane & 3) << 3;
  const u16* ga = A  + (m0 + srow) * K + sch;
  const u16* gb = Bw + (n0 + srow) * K + sch;
  u16* la = As + (wave << 10);
  u16* lb = Bs + (wave << 10);
  const long rstep = (long)16 * K;

  const int fr = lane & 15, fc = (lane >> 4) << 3;

  for (int k0 = 0; k0 < K; k0 += 32) {
    __syncthreads();
    gld16(ga + k0,         la);
    gld16(ga + k0 + rstep, la + 512);
    gld16(gb + k0,         lb);
    gld16(gb + k0 + rstep, lb + 512);
    __syncthreads();
    bf16x8 af[4], bf[4];
#pragma unroll
    for (int i = 0; i < 4; ++i)
      af[i] = as_bf(*(const u16x8*)&As[(wm + (i << 4) + fr) * 32 + fc]);
#pragma unroll
    for (int i = 0; i < 4; ++i)
      bf[i] = as_bf(*(const u16x8*)&Bs[(wn + (i << 4) + fr) * 32 + fc]);
#pragma unroll
    for (int mi = 0; mi < 4; ++mi)
#pragma unroll
      for (int ni = 0; ni < 4; ++ni)
        acc[mi][ni] = __builtin_amdgcn_mfma_f32_16x16x32_bf16(af[mi], bf[ni], acc[mi][ni], 0, 0, 0);
  }

  // epilogue target: q / k / v (tile boundaries align with 2048/2560)
  u16* Cb; int N2; long c0;
  if (bn < 16)      { Cb = Cq; N2 = 2048; c0 = n0; }
  else if (bn < 20) { Cb = Ck; N2 = 512;  c0 = n0 - 2048; }
  else              { Cb = Cv; N2 = 512;  c0 = n0 - 2560; }

  const int er = (lane >> 4) << 2, ec = lane & 15;
#pragma unroll
  for (int mi = 0; mi < 4; ++mi)
#pragma unroll
    for (int ni = 0; ni < 4; ++ni) {
      u16* cp = Cb + (m0 + wm + (mi << 4) + er) * N2 + (c0 + wn + (ni << 4) + ec);
#pragma unroll
      for (int r = 0; r < 4; ++r)
        cp[(long)r * N2] = f2bf(acc[mi][ni][r]);
    }
}

// ---------------------------------------------------------------------------
// Output projection: out[4096,2048] (fp32) = ctx @ Wo^T (both bf16)
// ---------------------------------------------------------------------------
__global__ __launch_bounds__(256) void gemm_o(
    const u16* __restrict__ A, const u16* __restrict__ Bw, float* __restrict__ C)
{
  constexpr int K = 2048, N = 2048;
  __shared__ u16 As[128 * 32];
  __shared__ u16 Bs[128 * 32];
  const int bx = blockIdx.x;
  const int bm = bx >> 4, bn = bx & 15;
  const int tid = threadIdx.x, wave = tid >> 6, lane = tid & 63;
  const int wm = (wave & 1) << 6, wn = (wave >> 1) << 6;
  const long m0 = (long)bm << 7, n0 = (long)bn << 7;

  f32x4 acc[4][4] = {};

  const int srow = (wave << 5) + (lane >> 2);
  const int sch  = (lane & 3) << 3;
  const u16* ga = A  + (m0 + srow) * K + sch;
  const u16* gb = Bw + (n0 + srow) * K + sch;
  u16* la = As + (wave << 10);
  u16* lb = Bs + (wave << 10);
  const long rstep = (long)16 * K;

  const int fr = lane & 15, fc = (lane >> 4) << 3;

  for (int k0 = 0; k0 < K; k0 += 32) {
    __syncthreads();
    gld16(ga + k0,         la);
    gld16(ga + k0 + rstep, la + 512);
    gld16(gb + k0,         lb);
    gld16(gb + k0 + rstep, lb + 512);
    __syncthreads();
    bf16x8 af[4], bf[4];
#pragma unroll
    for (int i = 0; i < 4; ++i)
      af[i] = as_bf(*(const u16x8*)&As[(wm + (i << 4) + fr) * 32 + fc]);
#pragma unroll
    for (int i = 0; i < 4; ++i)
      bf[i] = as_bf(*(const u16x8*)&Bs[(wn + (i << 4) + fr) * 32 + fc]);
#pragma unroll
    for (int mi = 0; mi < 4; ++mi)
#pragma unroll
      for (int ni = 0; ni < 4; ++ni)
        acc[mi][ni] = __builtin_amdgcn_mfma_f32_16x16x32_bf16(af[mi], bf[ni], acc[mi][ni], 0, 0, 0);
  }

  const int er = (lane >> 4) << 2, ec = lane & 15;
#pragma unroll
  for (int mi = 0; mi < 4; ++mi)
#pragma unroll
    for (int ni = 0; ni < 4; ++ni) {
      float* cp = C + (m0 + wm + (mi << 4) + er) * N + (n0 + wn + (ni << 4) + ec);
#pragma unroll
      for (int r = 0; r < 4; ++r)
        cp[(long)r * N] = acc[mi][ni][r];
    }
}

// ---------------------------------------------------------------------------
// RMSNorm + RoPE (unchanged from round 4 — verified)
// ---------------------------------------------------------------------------
__global__ __launch_bounds__(256) void norm_rope(
    u16* __restrict__ buf, const float* __restrict__ w,
    const float* __restrict__ cosb, const float* __restrict__ sinb,
    int sshift, float scale)
{
  const int row  = blockIdx.x * 4 + (threadIdx.x >> 6);
  const int lane = threadIdx.x & 63;
  const int s = (row >> sshift) & (S_LEN - 1);
  u16* p = buf + (long)row * HD;
  float t1 = bf2f(p[lane]), t2 = bf2f(p[lane + 64]);
  float ss = t1 * t1 + t2 * t2;
#pragma unroll
  for (int off = 32; off; off >>= 1) ss += __shfl_xor(ss, off);
  const float r = rsqrtf(ss * (1.0f / 128.0f) + 1e-5f);
  t1 *= r * w[lane];
  t2 *= r * w[lane + 64];
  const float* cp = cosb + s * HD;
  const float* sp = sinb + s * HD;
  const float o1 = (t1 * cp[lane]      - t2 * sp[lane])      * scale;
  const float o2 = (t2 * cp[lane + 64] + t1 * sp[lane + 64]) * scale;
  p[lane]      = f2bf(o1);
  p[lane + 64] = f2bf(o2);
}

// ---------------------------------------------------------------------------
// V (B*S, KV*HD) -> Vt (B*KV, HD, S)  (unchanged — verified)
// ---------------------------------------------------------------------------
__global__ __launch_bounds__(256) void transpose_v(const u16* __restrict__ v,
                                                   u16* __restrict__ vt)
{
  const int idx = blockIdx.x * 256 + threadIdx.x;
  const int t   = idx & (S_LEN - 1);
  const int hd0 = ((idx >> 11) & 15) << 3;
  const int bkv = idx >> 15;
  const u16* vp = v + ((long)(bkv >> 2) * S_LEN + t) * 512 + ((bkv & 3) << 7) + hd0;
  u16x8 d = *(const u16x8*)vp;
  u16* op = vt + ((long)bkv * HD + hd0) * S_LEN + t;
#pragma unroll
  for (int j = 0; j < 8; ++j) op[(long)j * S_LEN] = d[j];
}

// ---------------------------------------------------------------------------
// Flash attention, S^T/O^T formulation.
//   S^T = K Q^T  (A=K frags, B=Q frags — layouts identical, C col = q = fr)
//   softmax per q: in-lane over 32 vals + 2 shuffles (xor 16, 32)
//   P[q][t] bf16 in Ks overlay (b64 writes, swizzled, conflict-free)
//   O^T = V^T P^T (A=Vt frags from Vs, B=P frags via ds_read_b128)
// K/Vt staged via global_load_lds width-16.
// ---------------------------------------------------------------------------
__global__ __launch_bounds__(256, 2) void flash(
    const u16* __restrict__ q, const u16* __restrict__ k,
    const u16* __restrict__ vt, u16* __restrict__ ctx)
{
  __shared__ u16 Ks[128 * 128];   // K tile [t][d]; reused for P [q][t]
  __shared__ u16 Vs[128 * 128];   // Vt tile [hd][t]
  const int tid = threadIdx.x, wave = tid >> 6, lane = tid & 63;
  const int bx  = blockIdx.x;
  const int qtr = bx & 15;
  const int bh  = bx >> 4;                          // b*16+h
  const int qt  = (bx < 256) ? (15 - qtr) : qtr;    // balance causal wedge
  const int b   = bh >> 4, h = bh & 15;
  const int kv  = h >> 2;
  const int q0  = qt << 7;

  const int fr = lane & 15, fhi = lane >> 4;

  // Q fragments, B-operand layout (n=fr, k=fhi*8+j): qf[nq][kb]
  bf16x8 qf[2][4];
#pragma unroll
  for (int nq = 0; nq < 2; ++nq) {
    const long s = q0 + (wave << 5) + (nq << 4) + fr;
    const u16* qp = q + ((long)b * S_LEN + s) * DMODEL + h * HD;
#pragma unroll
    for (int kb = 0; kb < 4; ++kb)
      qf[nq][kb] = as_bf(*(const u16x8*)(qp + (kb << 5) + (fhi << 3)));
  }

  f32x4 O[8][2] = {};            // O^T: [hd-tile][q-tile], col q = fr
  float mS[2] = {-1e30f, -1e30f}, lS[2] = {0.f, 0.f};

  const u16* kbase = k + ((long)b * S_LEN) * 512 + kv * HD;
  const u16* vbase = vt + ((long)(b * NKV + kv)) * HD * S_LEN;

  for (int jt = 0; jt <= qt; ++jt) {
    const int t0 = jt << 7;
    __syncthreads();             // prev iter done with Ks(P) and Vs
    // stage K[t][d] and Vt[hd][t], chunk8 XOR swizzle on global side
#pragma unroll
    for (int i = 0; i < 8; ++i) {
      const int row = (wave << 5) + (i << 2) + fhi;
      const int gc  = fr ^ (row & 15);
      gld16(kbase + (long)(t0 + row) * 512 + (gc << 3),
            Ks + (((wave << 5) + (i << 2)) << 7));
      gld16(vbase + (long)row * S_LEN + t0 + (gc << 3),
            Vs + (((wave << 5) + (i << 2)) << 7));
    }
    __syncthreads();

    // S^T = K Q^T : Sac[mt][nq], rows t = mt*16 + (fhi*4+r), cols q
    f32x4 Sac[8][2] = {};
#pragma unroll
    for (int mt = 0; mt < 8; ++mt) {
      const int t = (mt << 4) + fr;
      bf16x8 kf[4];
#pragma unroll
      for (int kb = 0; kb < 4; ++kb) {
        const int cc = ((kb << 2) + fhi) ^ (t & 15);
        kf[kb] = as_bf(*(const u16x8*)&Ks[t * 128 + (cc << 3)]);
      }
#pragma unroll
      for (int nq = 0; nq < 2; ++nq)
#pragma unroll
        for (int kb = 0; kb < 4; ++kb)
          Sac[mt][nq] = __builtin_amdgcn_mfma_f32_16x16x32_bf16(kf[kb], qf[nq][kb], Sac[mt][nq], 0, 0, 0);
    }

    // causal mask on diagonal tile: t_in > q_in -> -inf
    if (jt == qt) {
      const int tb = fhi << 2;
#pragma unroll
      for (int mt = 0; mt < 8; ++mt)
#pragma unroll
        for (int nq = 0; nq < 2; ++nq) {
          const int qin = (wave << 5) + (nq << 4) + fr;
#pragma unroll
          for (int r = 0; r < 4; ++r)
            if ((mt << 4) + tb + r > qin) Sac[mt][nq][r] = -1e30f;
        }
    }

    // online softmax per q (= per lane, per nq)
#pragma unroll
    for (int nq = 0; nq < 2; ++nq) {
      float rmax = -1e30f;
#pragma unroll
      for (int mt = 0; mt < 8; ++mt)
#pragma unroll
        for (int r = 0; r < 4; ++r) rmax = fmaxf(rmax, Sac[mt][nq][r]);
      rmax = fmaxf(rmax, __shfl_xor(rmax, 16));
      rmax = fmaxf(rmax, __shfl_xor(rmax, 32));
      const float mn = fmaxf(mS[nq], rmax);
      const float al = __expf(mS[nq] - mn);
      mS[nq] = mn;
      float rsum = 0.f;
#pragma unroll
      for (int mt = 0; mt < 8; ++mt)
#pragma unroll
        for (int r = 0; r < 4; ++r) {
          const float e = __expf(Sac[mt][nq][r] - mn);
          Sac[mt][nq][r] = e;
          rsum += e;
        }
      rsum += __shfl_xor(rsum, 16);
      rsum += __shfl_xor(rsum, 32);
      lS[nq] = lS[nq] * al + rsum;
#pragma unroll
      for (int mh = 0; mh < 8; ++mh)
#pragma unroll
        for (int r = 0; r < 4; ++r) O[mh][nq][r] *= al;
    }

    __syncthreads();             // all waves done reading K from Ks

    // P[q][t] into Ks overlay: b64 writes, chunk8' = chunk8 ^ (q&7)
#pragma unroll
    for (int nq = 0; nq < 2; ++nq) {
      const int qrow = (wave << 5) + (nq << 4) + fr;
#pragma unroll
      for (int mt = 0; mt < 8; ++mt) {
        u16x4 pk;
#pragma unroll
        for (int r = 0; r < 4; ++r) pk[r] = f2bf(Sac[mt][nq][r]);
        const int c8 = (mt << 1) + (fhi >> 1);
        const int cs = c8 ^ (fr & 7);
        *(u16x4*)&Ks[qrow * 128 + (cs << 3) + ((fhi & 1) << 2)] = pk;
      }
    }
    asm volatile("" ::: "memory");

    // O^T += V^T P^T : A = Vt frags from Vs, B = P frags (wave-private rows)
    bf16x8 pf[2][4];
#pragma unroll
    for (int nq = 0; nq < 2; ++nq) {
      const int qrow = (wave << 5) + (nq << 4) + fr;
#pragma unroll
      for (int kt = 0; kt < 4; ++kt) {
        const int cs = ((kt << 2) + fhi) ^ (fr & 7);
        pf[nq][kt] = as_bf(*(const u16x8*)&Ks[qrow * 128 + (cs << 3)]);
      }
    }
#pragma unroll
    for (int mh = 0; mh < 8; ++mh) {
      const int hd = (mh << 4) + fr;
      bf16x8 vf[4];
#pragma unroll
      for (int kt = 0; kt < 4; ++kt) {
        const int cc = ((kt << 2) + fhi) ^ (hd & 15);
        vf[kt] = as_bf(*(const u16x8*)&Vs[hd * 128 + (cc << 3)]);
      }
#pragma unroll
      for (int nq = 0; nq < 2; ++nq)
#pragma unroll
        for (int kt = 0; kt < 4; ++kt)
          O[mh][nq] = __builtin_amdgcn_mfma_f32_16x16x32_bf16(vf[kt], pf[nq][kt], O[mh][nq], 0, 0, 0);
    }
  }

  // epilogue: lane holds col q = fr; rows hd = mh*16 + fhi*4 + r -> 8B stores
#pragma unroll
  for (int nq = 0; nq < 2; ++nq) {
    const float inv = 1.0f / lS[nq];
    const long s = q0 + (wave << 5) + (nq << 4) + fr;
    u16* cp = ctx + ((long)b * S_LEN + s) * DMODEL + h * HD;
#pragma unroll
    for (int mh = 0; mh < 8; ++mh) {
      u16x4 pk;
#pragma unroll
      for (int r = 0; r < 4; ++r) pk[r] = f2bf(O[mh][nq][r] * inv);
      *(u16x4*)(cp + (mh << 4) + (fhi << 2)) = pk;
    }
  }
}

// ---------------------------------------------------------------------------
extern "C" void kernel_launch(void* const* d_in, const int* in_sizes, int n_in,
                              void* d_out, int out_size, void* d_ws, size_t ws_size,
                              hipStream_t stream) {
  const float* x    = (const float*)d_in[0];
  // d_in[1] = mask (causal, analytic — unused)
  const float* cosb = (const float*)d_in[2];
  const float* sinb = (const float*)d_in[3];
  const float* Wq   = (const float*)d_in[4];
  const float* Wk   = (const float*)d_in[5];
  const float* Wv   = (const float*)d_in[6];
  const float* Wo   = (const float*)d_in[7];
  const float* qw   = (const float*)d_in[8];
  const float* kw   = (const float*)d_in[9];

  // d_out (33.55 MB fp32) doubles as scratch: qb | xb (each 16.78 MB bf16)
  u16* qb  = (u16*)d_out;            // (B*S, 2048) bf16
  u16* xb  = qb + 8388608;           // (B*S, 2048) bf16
  // ws: kb | vb | vtb | ctx(16.8MB; pre-flash holds Wall = Wq|Wk|Wv bf16)
  u16* kb  = (u16*)d_ws;             // 2097152 elems
  u16* vb  = kb  + 2097152;
  u16* vtb = vb  + 2097152;
  u16* ctx = vtb + 2097152;          // 8388608 elems
  u16* wall = ctx;                   // (3072, 2048) bf16 = 12.58 MB, dies at flash
  u16* wob  = kb;                    // (2048, 2048) bf16 spans kb+vb, born post-flash
  float* out = (float*)d_out;

  cvt1<<<dim3(4096), dim3(256), 0, stream>>>(x, xb, 1048576);
  cvt3<<<dim3(3072), dim3(256), 0, stream>>>(Wq, Wk, Wv, wall);
  gemm_qkv<<<dim3(768), dim3(256), 0, stream>>>(xb, wall, qb, kb, vb);
  norm_rope<<<dim3(16384), dim3(256), 0, stream>>>(qb, qw, cosb, sinb, 4, 0.08838834764831845f);
  norm_rope<<<dim3(4096),  dim3(256), 0, stream>>>(kb, kw, cosb, sinb, 2, 1.0f);
  transpose_v<<<dim3(1024), dim3(256), 0, stream>>>(vb, vtb);
  flash<<<dim3(512), dim3(256), 0, stream>>>(qb, kb, vtb, ctx);
  cvt1<<<dim3(2048), dim3(256), 0, stream>>>(Wo, wob, 524288);
  gemm_o<<<dim3(512), dim3(256), 0, stream>>>(ctx, wob, out);
}